// Round 4
// baseline (656.873 us; speedup 1.0000x reference)
//
#include <hip/hip_runtime.h>
#include <math.h>

#define NUSERS 50000
#define NITEMS 50000
#define NTOT   100000
#define NNODE  50000      // per direction
#define NCHUNK 196        // ceil(50000/256)
#define MTILES 6250       // 100000/16 row tiles
#define KDIM   512

typedef __attribute__((ext_vector_type(4))) float f32x4;
typedef __attribute__((ext_vector_type(8))) short short8;
typedef unsigned int u32;

#define AS1 __attribute__((address_space(1)))
#define AS3 __attribute__((address_space(3)))

static __device__ __forceinline__ unsigned short f2bf(float f) {
  unsigned int u = __float_as_uint(f);
  u += 0x7fffu + ((u >> 16) & 1u);
  return (unsigned short)(u >> 16);
}

static __device__ __forceinline__ void gload_lds16(const void* g, void* l) {
  __builtin_amdgcn_global_load_lds((const AS1 u32*)g, (AS3 u32*)l, 16, 0, 0);
}

// ---------------- pack W'' into MFMA B-fragment order -----------------
__global__ void pack_w_kernel(const float* __restrict__ w_ih,
                              const float* __restrict__ w_hh,
                              const float* __restrict__ b_ih,
                              const float* __restrict__ b_hh,
                              unsigned short* __restrict__ Wb,
                              float* __restrict__ bb) {
  int idx = blockIdx.x * 256 + threadIdx.x;       // 0 .. 512*512-1
  int j = idx & 7, l = (idx >> 3) & 63, ktt = idx >> 9;
  int kt = ktt & 15, tt = ktt >> 4;
  int g = tt * 16 + (l & 15);
  int k = kt * 32 + (l >> 4) * 8 + j;
  float v;
  if (g < 256)      v = (k < 384) ? w_ih[g * 384 + k] : w_hh[g * 128 + (k - 384)];
  else if (g < 384) v = (k < 384) ? w_ih[g * 384 + k] : 0.0f;
  else              v = (k < 384) ? 0.0f : w_hh[(g - 128) * 128 + (k - 384)];
  Wb[idx] = f2bf(v);
  if (idx < 512) {
    float b = (idx < 256) ? (b_ih[idx] + b_hh[idx])
            : (idx < 384) ? b_ih[idx]
                          : b_hh[idx - 128];
    bb[idx] = b;
  }
}

// ---------------- CSR build -----------------
__global__ void hist_kernel(const int* __restrict__ dst_g,
                            const int* __restrict__ dst_gr,
                            int* __restrict__ deg_j, int* __restrict__ deg_i, int E) {
  int i = blockIdx.x * 256 + threadIdx.x;
  if (i < E) atomicAdd(&deg_j[dst_g[i]], 1);
  else if (i < 2 * E) atomicAdd(&deg_i[dst_gr[i - E]], 1);
}

__global__ void chunksum_kernel(const int* __restrict__ deg_j,
                                const int* __restrict__ deg_i,
                                int* __restrict__ csum) {
  int c = blockIdx.x;                    // 0..2*NCHUNK-1
  const int* deg = (c < NCHUNK) ? deg_j : deg_i;
  int cc = (c < NCHUNK) ? c : c - NCHUNK;
  int t = threadIdx.x;
  int idx = cc * 256 + t;
  int v = (idx < NNODE) ? deg[idx] : 0;
  for (int off = 32; off; off >>= 1) v += __shfl_down(v, off, 64);
  __shared__ int wsum[4];
  if ((t & 63) == 0) wsum[t >> 6] = v;
  __syncthreads();
  if (t == 0) csum[c] = wsum[0] + wsum[1] + wsum[2] + wsum[3];
}

__global__ void chunkscan_kernel(const int* __restrict__ csum, int* __restrict__ coff) {
  int d = blockIdx.x;                    // 0 or 1
  const int* cs = csum + d * NCHUNK;
  int* co = coff + d * NCHUNK;
  int t = threadIdx.x, lane = t & 63, w = t >> 6;
  int v = (t < NCHUNK) ? cs[t] : 0;
  int x = v;
  for (int off = 1; off < 64; off <<= 1) {
    int y = __shfl_up(x, off, 64);
    if (lane >= off) x += y;
  }
  __shared__ int wt[4];
  if (lane == 63) wt[w] = x;
  __syncthreads();
  int add = 0;
  for (int k = 0; k < 4; ++k) if (k < w) add += wt[k];
  if (t < NCHUNK) co[t] = add + x - v;   // exclusive prefix
}

__global__ void localscan_kernel(const int* __restrict__ deg_j,
                                 const int* __restrict__ deg_i,
                                 const int* __restrict__ coff,
                                 int* __restrict__ rs_j, int* __restrict__ cur_j,
                                 int* __restrict__ rs_i, int* __restrict__ cur_i) {
  int c = blockIdx.x;
  bool dj = c < NCHUNK;
  const int* deg = dj ? deg_j : deg_i;
  int cc = dj ? c : c - NCHUNK;
  int* rs = dj ? rs_j : rs_i;
  int* cur = dj ? cur_j : cur_i;
  int base = coff[c];
  int t = threadIdx.x, lane = t & 63, w = t >> 6;
  int idx = cc * 256 + t;
  int v = (idx < NNODE) ? deg[idx] : 0;
  int x = v;
  for (int off = 1; off < 64; off <<= 1) {
    int y = __shfl_up(x, off, 64);
    if (lane >= off) x += y;
  }
  __shared__ int wt[4];
  if (lane == 63) wt[w] = x;
  __syncthreads();
  int add = 0;
  for (int k = 0; k < 4; ++k) if (k < w) add += wt[k];
  int ex = base + add + x - v;
  if (idx < NNODE) { rs[idx] = ex; cur[idx] = ex; }
}

// fill: one 16B record per edge: (src, eid, ts_bits, 0)
__global__ void fill_kernel(const int* __restrict__ src_g, const int* __restrict__ dst_g,
                            const float* __restrict__ t,
                            const int* __restrict__ src_gr, const int* __restrict__ dst_gr,
                            const float* __restrict__ t_r,
                            int* __restrict__ cur_j, int* __restrict__ cur_i,
                            int4* __restrict__ recP_j, int4* __restrict__ recP_i,
                            int E) {
  int i = blockIdx.x * 256 + threadIdx.x;
  if (i < E) {
    int pos = atomicAdd(&cur_j[dst_g[i]], 1);
    recP_j[pos] = make_int4(src_g[i], i, __float_as_int(t[i]), 0);
  } else if (i < 2 * E) {
    int k = i - E;
    int pos = atomicAdd(&cur_i[dst_gr[k]], 1);
    recP_i[pos] = make_int4(src_gr[k], k, __float_as_int(t_r[k]), 0);
  }
}

// ---------------- gather: mean-message + pack X row in A-fragment order ----------------
// packed k layout: [0,128)=mean src_mem, [128,256)=h*(deg>0), [256,320)=mean tenc,
// [320,384)=mean edge feat, [384,512)=h
// One wave per node. Records batched 64-at-a-time into registers, broadcast via
// v_readlane. Feature loads are float4: si row = 32 lanes (half selects edge pair
// member), ef row = 16 lanes (quarter selects one of 4 edges). 8 edges per trip.
__global__ __launch_bounds__(256) void gather_kernel(
    const float* __restrict__ si, const float* __restrict__ sj,
    const float* __restrict__ si_r, const float* __restrict__ sj_r,
    const float* __restrict__ e, const float* __restrict__ e_r,
    const int* __restrict__ rs_j, const int* __restrict__ rs_i,
    const int* __restrict__ deg_j, const int* __restrict__ deg_i,
    const int4* __restrict__ recP_j, const int4* __restrict__ recP_i,
    unsigned short* __restrict__ Xb) {
  __shared__ __align__(16) unsigned short rowbuf[4][512];
  int wid = threadIdx.x >> 6, lane = threadIdx.x & 63;
  int node = blockIdx.x * 4 + wid;                 // 0..99999
  bool user = node < NUSERS;
  int idx = user ? node : node - NUSERS;
  const float* smem = user ? si_r : si;
  const float* h    = user ? sj_r : sj;
  const float* ef   = user ? e_r : e;
  int start = (user ? rs_i : rs_j)[idx];
  int deg   = (user ? deg_i : deg_j)[idx];
  const int4* rec = user ? recP_i : recP_j;

  int half = lane >> 5, l32 = lane & 31;
  int quar = lane >> 4, l16 = lane & 15;
  // freq[lane] = 10^(-9*lane/63)
  float freq = __expf((float)lane * -0.3289407276f);

  f32x4 accS = {0.f, 0.f, 0.f, 0.f};
  f32x4 accE = {0.f, 0.f, 0.f, 0.f};
  float accT = 0.f;

  for (int c0 = 0; c0 < deg; c0 += 64) {
    int nrec = min(64, deg - c0);
    int rlx = 0, rly = 0, rlz = 0;
    if (lane < nrec) {
      int4 r = rec[start + c0 + lane];
      rlx = r.x; rly = r.y; rlz = r.z;
    }
    for (int i = 0; i < nrec; i += 8) {
      int srow[8], erow[8];
      float tsv[8], wj[8];
#pragma unroll
      for (int j = 0; j < 8; ++j) {
        int ei = i + j;
        int eidx = (ei < nrec) ? ei : nrec - 1;
        wj[j] = (ei < nrec) ? 1.0f : 0.0f;
        srow[j] = __builtin_amdgcn_readlane(rlx, eidx);
        erow[j] = __builtin_amdgcn_readlane(rly, eidx);
        tsv[j]  = __int_as_float(__builtin_amdgcn_readlane(rlz, eidx));
      }
      // si: 4 instructions, each covers 2 edges (lane-half selects member)
      f32x4 sv[4]; float sw[4];
#pragma unroll
      for (int p = 0; p < 4; ++p) {
        int rsel = half ? srow[2 * p + 1] : srow[2 * p];
        sw[p]    = half ? wj[2 * p + 1]   : wj[2 * p];
        sv[p] = *(const f32x4*)(smem + (size_t)rsel * 128 + l32 * 4);
      }
      // ef: 2 instructions, each covers 4 edges (lane-quarter selects member)
      f32x4 ev[2]; float ew[2];
#pragma unroll
      for (int p = 0; p < 2; ++p) {
        int b = 4 * p;
        int rlo = (quar & 1) ? erow[b + 1] : erow[b];
        int rhi = (quar & 1) ? erow[b + 3] : erow[b + 2];
        int rsel = (quar & 2) ? rhi : rlo;
        float wlo = (quar & 1) ? wj[b + 1] : wj[b];
        float whi = (quar & 1) ? wj[b + 3] : wj[b + 2];
        ew[p] = (quar & 2) ? whi : wlo;
        ev[p] = *(const f32x4*)(ef + (size_t)rsel * 64 + l16 * 4);
      }
      // time encode: all 64 lanes per edge (feature = lane)
#pragma unroll
      for (int j = 0; j < 8; ++j)
        accT += wj[j] * __cosf(tsv[j] * freq);
#pragma unroll
      for (int p = 0; p < 4; ++p) accS += sv[p] * sw[p];
#pragma unroll
      for (int p = 0; p < 2; ++p) accE += ev[p] * ew[p];
    }
  }

  // cross-lane combine: accS over halves; accE over quarters
#pragma unroll
  for (int k = 0; k < 4; ++k) {
    accS[k] += __shfl_xor(accS[k], 32);
    float t1 = accE[k] + __shfl_xor(accE[k], 32);
    accE[k] = t1 + __shfl_xor(t1, 16);
  }

  float invc = (deg > 0) ? 1.0f / (float)deg : 0.0f;
  float hz   = (deg > 0) ? 1.0f : 0.0f;
  f32x4 hv = *(const f32x4*)(h + (size_t)idx * 128 + l32 * 4);

  unsigned short* rb = rowbuf[wid];
  if (half == 0) {
    ushort4 s4, h4a, h4b;
    s4.x = f2bf(accS[0] * invc); s4.y = f2bf(accS[1] * invc);
    s4.z = f2bf(accS[2] * invc); s4.w = f2bf(accS[3] * invc);
    h4a.x = f2bf(hv[0] * hz); h4a.y = f2bf(hv[1] * hz);
    h4a.z = f2bf(hv[2] * hz); h4a.w = f2bf(hv[3] * hz);
    h4b.x = f2bf(hv[0]); h4b.y = f2bf(hv[1]);
    h4b.z = f2bf(hv[2]); h4b.w = f2bf(hv[3]);
    *(ushort4*)(rb + 4 * l32)       = s4;
    *(ushort4*)(rb + 128 + 4 * l32) = h4a;
    *(ushort4*)(rb + 384 + 4 * l32) = h4b;
  }
  rb[256 + lane] = f2bf(accT * invc);
  if (lane < 16) {
    ushort4 e4;
    e4.x = f2bf(accE[0] * invc); e4.y = f2bf(accE[1] * invc);
    e4.z = f2bf(accE[2] * invc); e4.w = f2bf(accE[3] * invc);
    *(ushort4*)(rb + 320 + 4 * l16) = e4;
  }
  __syncthreads();

  // transpose-write in A-fragment order: lane owns k = lane*8 .. lane*8+8
  int rt = node >> 4, m = node & 15;
  int kt = lane >> 2, q = lane & 3;
  short8 vv = *(const short8*)(rb + lane * 8);
  *(short8*)(Xb + (((size_t)rt * 16 + kt) * 64 + q * 16 + m) * 8) = vv;
}

// ---------------- GEMM (100000 x 512) @ W''^T with fused GRU epilogue ----------------
__global__ __launch_bounds__(512, 2) void gemm_gru_kernel(
    const unsigned short* __restrict__ Xb,
    const unsigned short* __restrict__ Wb,
    const float* __restrict__ bb,
    const float* __restrict__ sj_r,
    const float* __restrict__ sj,
    float* __restrict__ out) {
  __shared__ __align__(16) unsigned short sB[32768];   // 64 KB
  int wid = threadIdx.x >> 6, lane = threadIdx.x & 63;
  int mtile = blockIdx.x * 8 + wid;
  bool valid = mtile < MTILES;
  int col16 = lane & 15, quad = lane >> 4;

  f32x4 acc[32];
#pragma unroll
  for (int t = 0; t < 32; ++t) acc[t] = (f32x4)0.0f;

  const unsigned short* Abase = Xb + (size_t)(valid ? mtile : 0) * 8192;

  for (int s = 0; s < 8; ++s) {
#pragma unroll
    for (int i = 0; i < 8; ++i) {
      int c = wid * 8 + i;
      int tt = c >> 1, kt = s * 2 + (c & 1);
      const unsigned short* g = Wb + ((size_t)(tt * 16 + kt) * 64 + lane) * 8;
      gload_lds16(g, sB + c * 512);
    }
    __syncthreads();
    if (valid) {
      short8 a0 = *(const short8*)(Abase + (size_t)(s * 2) * 512 + lane * 8);
      short8 a1 = *(const short8*)(Abase + (size_t)(s * 2 + 1) * 512 + lane * 8);
#pragma unroll
      for (int t = 0; t < 32; ++t) {
        short8 b0 = *(const short8*)(sB + (t * 2) * 512 + lane * 8);
        short8 b1 = *(const short8*)(sB + (t * 2 + 1) * 512 + lane * 8);
        acc[t] = __builtin_amdgcn_mfma_f32_16x16x32_bf16(a0, b0, acc[t], 0, 0, 0);
        acc[t] = __builtin_amdgcn_mfma_f32_16x16x32_bf16(a1, b1, acc[t], 0, 0, 0);
      }
    }
    __syncthreads();
  }

  if (!valid) return;
  int m0 = mtile * 16;
#pragma unroll
  for (int t = 0; t < 8; ++t) {
    int c = t * 16 + col16;
    float bbr = bb[c], bbz = bb[128 + c], bbn = bb[256 + c], bbh = bb[384 + c];
#pragma unroll
    for (int r = 0; r < 4; ++r) {
      int row = m0 + quad * 4 + r;
      float rp  = acc[t][r]      + bbr;
      float zp  = acc[t + 8][r]  + bbz;
      float inp = acc[t + 16][r] + bbn;
      float hnp = acc[t + 24][r] + bbh;
      float rg = 1.0f / (1.0f + __expf(-rp));
      float zg = 1.0f / (1.0f + __expf(-zp));
      float ng = tanhf(inp + rg * hnp);
      float hv = (row < NUSERS) ? sj_r[(size_t)row * 128 + c]
                                : sj[(size_t)(row - NUSERS) * 128 + c];
      out[(size_t)row * 128 + c] = (1.0f - zg) * ng + zg * hv;
    }
  }
}

extern "C" void kernel_launch(void* const* d_in, const int* in_sizes, int n_in,
                              void* d_out, int out_size, void* d_ws, size_t ws_size,
                              hipStream_t stream) {
  const float* si   = (const float*)d_in[0];
  const float* sj   = (const float*)d_in[1];
  const float* si_r = (const float*)d_in[2];
  const float* sj_r = (const float*)d_in[3];
  const float* t    = (const float*)d_in[4];
  const float* t_r  = (const float*)d_in[5];
  const float* e    = (const float*)d_in[6];
  const float* e_r  = (const float*)d_in[7];
  const float* w_ih = (const float*)d_in[8];
  const float* w_hh = (const float*)d_in[9];
  const float* b_ih = (const float*)d_in[10];
  const float* b_hh = (const float*)d_in[11];
  const int* src_g  = (const int*)d_in[12];
  const int* dst_g  = (const int*)d_in[13];
  const int* src_gr = (const int*)d_in[14];
  const int* dst_gr = (const int*)d_in[15];
  int E = in_sizes[4];

  // workspace layout (16B-aligned head first)
  unsigned short* Xb = (unsigned short*)d_ws;          // 51,200,000 shorts (102.4 MB)
  unsigned short* Wb = Xb + (size_t)MTILES * 8192;     // 262144 shorts
  float* bb   = (float*)(Wb + 262144);                 // 512
  int* deg_j  = (int*)(bb + 512);                      // 50000  (memset target, with deg_i)
  int* deg_i  = deg_j + NNODE;                         // 50000
  int* rs_j   = deg_i + NNODE;                         // 50000
  int* rs_i   = rs_j + NNODE;                          // 50000
  int* cur_j  = rs_i + NNODE;                          // 50000
  int* cur_i  = cur_j + NNODE;                         // 50000
  int* csum   = cur_i + NNODE;                         // 2*NCHUNK
  int* coff   = csum + 2 * NCHUNK;                     // 2*NCHUNK (ends 16B-aligned)
  int4* recP_j = (int4*)(coff + 2 * NCHUNK);           // E int4
  int4* recP_i = recP_j + E;                           // E int4

  hipMemsetAsync(deg_j, 0, 2 * NNODE * sizeof(int), stream);

  pack_w_kernel<<<(512 * 512) / 256, 256, 0, stream>>>(w_ih, w_hh, b_ih, b_hh, Wb, bb);

  int blks2E = (2 * E + 255) / 256;
  hist_kernel<<<blks2E, 256, 0, stream>>>(dst_g, dst_gr, deg_j, deg_i, E);
  chunksum_kernel<<<2 * NCHUNK, 256, 0, stream>>>(deg_j, deg_i, csum);
  chunkscan_kernel<<<2, 256, 0, stream>>>(csum, coff);
  localscan_kernel<<<2 * NCHUNK, 256, 0, stream>>>(deg_j, deg_i, coff, rs_j, cur_j, rs_i, cur_i);
  fill_kernel<<<blks2E, 256, 0, stream>>>(src_g, dst_g, t, src_gr, dst_gr, t_r,
                                          cur_j, cur_i, recP_j, recP_i, E);

  gather_kernel<<<NTOT / 4, 256, 0, stream>>>(si, sj, si_r, sj_r, e, e_r,
                                              rs_j, rs_i, deg_j, deg_i,
                                              recP_j, recP_i, Xb);

  float* out = (float*)d_out;
  gemm_gru_kernel<<<(MTILES + 7) / 8, 512, 0, stream>>>(Xb, Wb, bb, sj_r, sj, out);
}